// Round 4
// baseline (956.159 us; speedup 1.0000x reference)
//
#include <hip/hip_runtime.h>
#include <cstddef>
#include <cstdint>

#define S_TOK 8192
#define DDIM  2048
#define NEXP  64
#define CAPTY 128
#define KC    64
#define TPB   64                       // tokens per chunk
#define NBLK  (S_TOK / TPB)            // 128 chunks
#define SPLITK 8
#define KPER  (DDIM / SPLITK)          // 256
#define SEC   ((size_t)S_TOK * NEXP * CAPTY)   // 67,108,864
#define NGEMM (NBLK * SPLITK)          // 1024 blocks, 4/CU -> fully resident

// LDS overlay: gemm staging tiles vs softmax probs (used after gemm phase)
struct GemmSm { float xs[KC][TPB]; float ws2[KC][NEXP]; };       // 32,768 B
struct SoftSm { float probs[TPB][NEXP + 1]; int sexp[TPB]; };    // 16,896 B
union SMemU { GemmSm g; SoftSm s; };

// ---------------------------------------------------------------------------
// Mega kernel: 1024 blocks (all co-resident). Phase 1: split-K fp32 GEMM
// (block = token-chunk tc x k-part kp). Phase 2 (last split-K arrival per
// chunk only): softmax/argmax/rank/hist. Phase 3 (all blocks): zero-fill a
// contiguous 524 KB slice of the 537 MB output. Reads happen while nobody
// writes; writes stream at full BW afterwards. No block turnover -> no
// slot-starvation (the round-3 failure mode).
// ---------------------------------------------------------------------------
__global__ __launch_bounds__(256)
void mega_kernel(const float* __restrict__ x, const float* __restrict__ wg,
                 float* __restrict__ part, float* __restrict__ gate_s,
                 int* __restrict__ expert, int* __restrict__ rank,
                 int* __restrict__ hist, float* __restrict__ partial_g,
                 int* __restrict__ done, float* __restrict__ out)
{
    __shared__ SMemU sm;
    __shared__ int s_old;
    const int tid = threadIdx.x;
    const int g   = blockIdx.x;             // 0..1023
    const int kp  = g & (SPLITK - 1);
    const int tc  = g >> 3;
    const int t_base = tc * TPB;
    const int k_base = kp * KPER;
    const int e4 = tid & 15;                // experts 4*e4..+3
    const int tg = tid >> 4;                // tokens  4*tg..+3

    // ------------------- phase 1: GEMM -------------------
    float acc[4][4];
#pragma unroll
    for (int i = 0; i < 4; ++i)
#pragma unroll
        for (int j = 0; j < 4; ++j) acc[i][j] = 0.0f;

    for (int kc0 = 0; kc0 < KPER; kc0 += KC) {
        const int kc = k_base + kc0;
        __syncthreads();
#pragma unroll
        for (int m = 0; m < 4; ++m) {
            int idx = tid + 256 * m;        // 0..1023
            int t = idx & 63;
            int c = idx >> 6;               // float4 column 0..15
            float4 v = *(const float4*)(x + (size_t)(t_base + t) * DDIM + kc + c * 4);
            sm.g.xs[c * 4 + 0][t] = v.x;
            sm.g.xs[c * 4 + 1][t] = v.y;
            sm.g.xs[c * 4 + 2][t] = v.z;
            sm.g.xs[c * 4 + 3][t] = v.w;
            float4 w = *(const float4*)(wg + (size_t)t * DDIM + kc + c * 4);
            sm.g.ws2[c * 4 + 0][t] = w.x;
            sm.g.ws2[c * 4 + 1][t] = w.y;
            sm.g.ws2[c * 4 + 2][t] = w.z;
            sm.g.ws2[c * 4 + 3][t] = w.w;
        }
        __syncthreads();
#pragma unroll 8
        for (int k = 0; k < KC; ++k) {
            float4 wv = *(const float4*)&sm.g.ws2[k][e4 * 4];
            float2 xa = *(const float2*)&sm.g.xs[k][tg * 4];
            float2 xb = *(const float2*)&sm.g.xs[k][tg * 4 + 2];
            float xv0 = xa.x, xv1 = xa.y, xv2 = xb.x, xv3 = xb.y;
            acc[0][0] += xv0 * wv.x; acc[0][1] += xv0 * wv.y;
            acc[0][2] += xv0 * wv.z; acc[0][3] += xv0 * wv.w;
            acc[1][0] += xv1 * wv.x; acc[1][1] += xv1 * wv.y;
            acc[1][2] += xv1 * wv.z; acc[1][3] += xv1 * wv.w;
            acc[2][0] += xv2 * wv.x; acc[2][1] += xv2 * wv.y;
            acc[2][2] += xv2 * wv.z; acc[2][3] += xv2 * wv.w;
            acc[3][0] += xv3 * wv.x; acc[3][1] += xv3 * wv.y;
            acc[3][2] += xv3 * wv.z; acc[3][3] += xv3 * wv.w;
        }
    }

#pragma unroll
    for (int i = 0; i < 4; ++i) {
        float4 v = make_float4(acc[i][0], acc[i][1], acc[i][2], acc[i][3]);
        *(float4*)(part + ((size_t)kp * S_TOK + t_base + tg * 4 + i) * NEXP + e4 * 4) = v;
    }

    // arrival count for this token chunk
    __threadfence();
    __syncthreads();
    if (tid == 0) s_old = atomicAdd(&done[tc], 1);
    __syncthreads();

    // ---------- phase 2: softmax/argmax/rank/hist (last arrival only) ------
    if (s_old == SPLITK - 1) {
        __threadfence();                    // acquire: all 8 partials visible

        const int t = tid >> 2, q = tid & 3;    // 4 threads per token
        const int tok = t_base + t;
#pragma unroll
        for (int jj = 0; jj < 4; ++jj) {
            float4 a = make_float4(0.f, 0.f, 0.f, 0.f);
#pragma unroll
            for (int kpp = 0; kpp < SPLITK; ++kpp) {
                float4 v = *(const float4*)(part + ((size_t)kpp * S_TOK + tok) * NEXP + q * 16 + jj * 4);
                a.x += v.x; a.y += v.y; a.z += v.z; a.w += v.w;
            }
            sm.s.probs[t][q * 16 + jj * 4 + 0] = a.x;
            sm.s.probs[t][q * 16 + jj * 4 + 1] = a.y;
            sm.s.probs[t][q * 16 + jj * 4 + 2] = a.z;
            sm.s.probs[t][q * 16 + jj * 4 + 3] = a.w;
        }
        __syncthreads();

        if (tid < TPB) {                    // one thread per token
            const int t2 = tid, tok2 = t_base + t2;
            float m = -1e30f; int am = 0;
            for (int e = 0; e < NEXP; ++e) {
                float v = sm.s.probs[t2][e];
                if (v > m) { m = v; am = e; }       // strict > = np.argmax
            }
            float s = 0.0f;
            for (int e = 0; e < NEXP; ++e) s += __expf(sm.s.probs[t2][e] - m);
            float rcp = 1.0f / s;                   // top-1 gate value
            for (int e = 0; e < NEXP; ++e)
                sm.s.probs[t2][e] = __expf(sm.s.probs[t2][e] - m) * rcp;
            sm.s.sexp[t2] = am;
            gate_s[tok2] = rcp;
            expert[tok2] = am;
        }
        __syncthreads();

        if (tid < TPB) {                    // rank within chunk (token order)
            const int t2 = tid;
            const int am = sm.s.sexp[t2];
            int r = 0;
            for (int u = 0; u < t2; ++u) r += (sm.s.sexp[u] == am) ? 1 : 0;
            rank[t_base + t2] = r;
        } else if (tid < 2 * TPB) {         // per-expert histogram + gate sums
            const int e = tid - TPB;
            float pg = 0.0f; int cnt = 0;
            for (int u = 0; u < TPB; ++u) {
                pg  += sm.s.probs[u][e];
                cnt += (sm.s.sexp[u] == e) ? 1 : 0;
            }
            partial_g[tc * NEXP + e] = pg;
            hist[tc * NEXP + e]      = cnt;
        }
    }

    // ------------------- phase 3: zero-fill slice -------------------
    {
        float4* out4 = (float4*)out;
        const size_t base4 = (size_t)g * 32768;     // 2*SEC/4 / 1024 blocks
        float4 z = make_float4(0.f, 0.f, 0.f, 0.f);
#pragma unroll 4
        for (int it = 0; it < 128; ++it)
            out4[base4 + (size_t)it * 256 + tid] = z;
        if (g == 0 && tid == 0) out[2 * SEC] = 0.0f;   // odd last element
    }
}

// ---------------------------------------------------------------------------
// Kernel 2: per-expert exclusive scan over 128 chunks + l_aux + scatter.
// Runs after mega -> all zeros written; safe to scatter and write out[0].
// ---------------------------------------------------------------------------
__global__ __launch_bounds__(256)
void scan_scatter_kernel(const int* __restrict__ hist, const float* __restrict__ partial_g,
                         const float* __restrict__ gate_s, const int* __restrict__ expert,
                         const int* __restrict__ rank, float* __restrict__ out)
{
    __shared__ int base_s[NBLK][NEXP];      // 32 KB
    const int tid = threadIdx.x;

    if (tid < NEXP) {                       // wave 0: serial scan per expert
        const int e = tid;
        int base = 0; float sg = 0.0f;
        for (int c = 0; c < NBLK; ++c) {
            base_s[c][e] = base;
            base += hist[c * NEXP + e];
            sg  += partial_g[c * NEXP + e];
        }
        float v = sg * (float)base;         // sum_gates[e] * pre-drop count[e]
#pragma unroll
        for (int off = 32; off > 0; off >>= 1) v += __shfl_down(v, off);
        if (e == 0) out[0] = v * (64.0f / (8192.0f * 8192.0f));   // l_aux
    }
    __syncthreads();

    for (int s = tid; s < S_TOK; s += 256) {
        const int e = expert[s];
        const int loc = base_s[s >> 6][e] + rank[s];
        if (loc < CAPTY) {
            size_t idx = 1 + (size_t)s * (NEXP * CAPTY) + (size_t)e * CAPTY + loc;
            out[idx]       = gate_s[s];     // combine1_sec
            out[idx + SEC] = 1.0f;          // dispatch_mask
        }
    }
}

extern "C" void kernel_launch(void* const* d_in, const int* in_sizes, int n_in,
                              void* d_out, int out_size, void* d_ws, size_t ws_size,
                              hipStream_t stream)
{
    const float* x  = (const float*)d_in[0];
    const float* wg = (const float*)d_in[1];
    float* out = (float*)d_out;
    char* ws = (char*)d_ws;

    float* part      = (float*)(ws + 0);                       // 16 MB
    size_t off = (size_t)SPLITK * S_TOK * NEXP * sizeof(float);
    float* gate_s    = (float*)(ws + off);          off += 32768;
    int*   expert    = (int*)  (ws + off);          off += 32768;
    int*   rank      = (int*)  (ws + off);          off += 32768;
    int*   hist      = (int*)  (ws + off);          off += 32768;
    float* partial_g = (float*)(ws + off);          off += 32768;
    int*   done      = (int*)  (ws + off);                     // 128 ints

    // ws is poisoned 0xAA before every launch: zero the arrival counters
    hipMemsetAsync(done, 0, NBLK * sizeof(int), stream);

    mega_kernel<<<NGEMM, 256, 0, stream>>>(x, wg, part, gate_s, expert, rank,
                                           hist, partial_g, done, out);
    scan_scatter_kernel<<<1, 256, 0, stream>>>(hist, partial_g, gate_s, expert, rank, out);
}

// Round 5
// 595.462 us; speedup vs baseline: 1.6057x; 1.6057x over previous
//
#include <hip/hip_runtime.h>
#include <cstddef>
#include <cstdint>

#define S_TOK 8192
#define DDIM  2048
#define NEXP  64
#define CAPTY 128
#define KC    64
#define TPB   64                       // tokens per chunk
#define NBLK  (S_TOK / TPB)            // 128 chunks
#define SPLITK 8
#define KPER  (DDIM / SPLITK)          // 256
#define SEC   ((size_t)S_TOK * NEXP * CAPTY)   // 67,108,864

// ---------------------------------------------------------------------------
// Kernel 1: split-K fp32 GEMM, coalesced staging.
//  x staged t-major xs[t][k] (row pad 72 floats: 16-B aligned, 2-way banks).
//  wg staged k-major ws[k][e] (scatter global loads; wg slice is L2-hot).
//  Thread (el=tid&15, tg=tid>>4): tokens t=tg+16i, experts e=4*el..4*el+3.
//  Inner loop: 4-k quads, all-b128 LDS reads, 64 FMAs per quad.
// ---------------------------------------------------------------------------
__global__ __launch_bounds__(256)
void gate_gemm_kernel(const float* __restrict__ x, const float* __restrict__ wg,
                      float* __restrict__ part)
{
    __shared__ float xs[TPB][72];       // 18,432 B
    __shared__ float ws[KC][NEXP];      // 16,384 B  (34.8 KB total -> 4 blk/CU)

    const int tid = threadIdx.x;
    const int el  = tid & 15;           // experts 4*el..4*el+3
    const int tg  = tid >> 4;           // tokens  tg, tg+16, tg+32, tg+48
    const int kp  = blockIdx.x & (SPLITK - 1);
    const int tc  = blockIdx.x >> 3;
    const int t_base = tc * TPB;
    const int k_base = kp * KPER;

    float acc[4][4];                    // [token i][expert j]
#pragma unroll
    for (int i = 0; i < 4; ++i)
#pragma unroll
        for (int j = 0; j < 4; ++j) acc[i][j] = 0.0f;

    for (int kc0 = 0; kc0 < KPER; kc0 += KC) {
        const int kc = k_base + kc0;
        __syncthreads();
        // stage x: 16 consecutive lanes read 256 contiguous bytes of one row
#pragma unroll
        for (int m = 0; m < 4; ++m) {
            int idx = tid + 256 * m;        // 0..1023
            int t = idx >> 4;               // row 0..63
            int c = idx & 15;               // float4 col 0..15
            float4 v = *(const float4*)(x + (size_t)(t_base + t) * DDIM + kc + c * 4);
            *(float4*)&xs[t][c * 4] = v;    // aligned b128, ~2-way banks
        }
        // stage wg: scatter along k (L2-absorbed), conflict-free b32 LDS writes
#pragma unroll
        for (int m = 0; m < 4; ++m) {
            int idx = tid + 256 * m;
            int e = idx & 63;               // expert row
            int c = idx >> 6;               // float4 col 0..15
            float4 w = *(const float4*)(wg + (size_t)e * DDIM + kc + c * 4);
            ws[c * 4 + 0][e] = w.x;
            ws[c * 4 + 1][e] = w.y;
            ws[c * 4 + 2][e] = w.z;
            ws[c * 4 + 3][e] = w.w;
        }
        __syncthreads();

#pragma unroll
        for (int k4 = 0; k4 < KC; k4 += 4) {
            float4 xv[4], wv[4];
#pragma unroll
            for (int i = 0; i < 4; ++i)
                xv[i] = *(const float4*)&xs[tg + 16 * i][k4];   // banks disjoint
#pragma unroll
            for (int j = 0; j < 4; ++j)
                wv[j] = *(const float4*)&ws[k4 + j][el * 4];    // 2-way banks
#pragma unroll
            for (int i = 0; i < 4; ++i) {
                acc[i][0] += xv[i].x * wv[0].x; acc[i][1] += xv[i].x * wv[0].y;
                acc[i][2] += xv[i].x * wv[0].z; acc[i][3] += xv[i].x * wv[0].w;
                acc[i][0] += xv[i].y * wv[1].x; acc[i][1] += xv[i].y * wv[1].y;
                acc[i][2] += xv[i].y * wv[1].z; acc[i][3] += xv[i].y * wv[1].w;
                acc[i][0] += xv[i].z * wv[2].x; acc[i][1] += xv[i].z * wv[2].y;
                acc[i][2] += xv[i].z * wv[2].z; acc[i][3] += xv[i].z * wv[2].w;
                acc[i][0] += xv[i].w * wv[3].x; acc[i][1] += xv[i].w * wv[3].y;
                acc[i][2] += xv[i].w * wv[3].z; acc[i][3] += xv[i].w * wv[3].w;
            }
        }
    }

#pragma unroll
    for (int i = 0; i < 4; ++i) {
        int t = tg + 16 * i;
        float4 v = make_float4(acc[i][0], acc[i][1], acc[i][2], acc[i][3]);
        *(float4*)(part + ((size_t)kp * S_TOK + t_base + t) * NEXP + el * 4) = v;
    }
}

// ---------------------------------------------------------------------------
// Kernel 2: reduce split-K partials + softmax/argmax/rank/hist per chunk.
// 128 blocks x 256 threads (4 threads per token for the reduction).
// ---------------------------------------------------------------------------
__global__ __launch_bounds__(256)
void softmax_kernel(const float* __restrict__ part,
                    float* __restrict__ gate_s, int* __restrict__ expert,
                    int* __restrict__ rank, int* __restrict__ hist,
                    float* __restrict__ partial_g)
{
    __shared__ float probs[TPB][NEXP + 1];
    __shared__ int   sexp[TPB];

    const int tid = threadIdx.x;
    const int t_base = blockIdx.x * TPB;
    const int t = tid >> 2, q = tid & 3;    // 4 threads per token
    const int tok = t_base + t;

#pragma unroll
    for (int jj = 0; jj < 4; ++jj) {
        float4 a = make_float4(0.f, 0.f, 0.f, 0.f);
#pragma unroll
        for (int kpp = 0; kpp < SPLITK; ++kpp) {
            float4 v = *(const float4*)(part + ((size_t)kpp * S_TOK + tok) * NEXP + q * 16 + jj * 4);
            a.x += v.x; a.y += v.y; a.z += v.z; a.w += v.w;
        }
        probs[t][q * 16 + jj * 4 + 0] = a.x;
        probs[t][q * 16 + jj * 4 + 1] = a.y;
        probs[t][q * 16 + jj * 4 + 2] = a.z;
        probs[t][q * 16 + jj * 4 + 3] = a.w;
    }
    __syncthreads();

    if (tid < TPB) {                    // one thread per token
        const int t2 = tid, tok2 = t_base + t2;
        float m = -1e30f; int am = 0;
        for (int e = 0; e < NEXP; ++e) {
            float v = probs[t2][e];
            if (v > m) { m = v; am = e; }       // strict > = np.argmax
        }
        float s = 0.0f;
        for (int e = 0; e < NEXP; ++e) s += __expf(probs[t2][e] - m);
        float rcp = 1.0f / s;                   // top-1 gate value
        for (int e = 0; e < NEXP; ++e)
            probs[t2][e] = __expf(probs[t2][e] - m) * rcp;
        sexp[t2] = am;
        gate_s[tok2] = rcp;
        expert[tok2] = am;
    }
    __syncthreads();

    if (tid < TPB) {                    // rank within chunk (token order)
        const int t2 = tid;
        const int am = sexp[t2];
        int r = 0;
        for (int u = 0; u < t2; ++u) r += (sexp[u] == am) ? 1 : 0;
        rank[t_base + t2] = r;
    } else if (tid < 2 * TPB) {         // per-expert histogram + gate sums
        const int e = tid - TPB;
        float pg = 0.0f; int cnt = 0;
        for (int u = 0; u < TPB; ++u) {
            pg  += probs[u][e];
            cnt += (sexp[u] == e) ? 1 : 0;
        }
        partial_g[blockIdx.x * NEXP + e] = pg;
        hist[blockIdx.x * NEXP + e]      = cnt;
    }
}

// ---------------------------------------------------------------------------
// Kernel 3: per-expert exclusive scan over 128 chunks + l_aux -> ws
// (runs BEFORE the big fill so only the tiny scatter trails it)
// ---------------------------------------------------------------------------
__global__ __launch_bounds__(64)
void scan_kernel(const int* __restrict__ hist, const float* __restrict__ partial_g,
                 int* __restrict__ chunk_base, float* __restrict__ l_aux_ws)
{
    int e = threadIdx.x;   // 0..63, one wave
    int base = 0;
    float sg = 0.0f;
    for (int c = 0; c < NBLK; ++c) {
        chunk_base[c * NEXP + e] = base;
        base += hist[c * NEXP + e];
        sg   += partial_g[c * NEXP + e];
    }
    float v = sg * (float)base;            // sum_gates[e] * pre-drop count[e]
#pragma unroll
    for (int off = 32; off > 0; off >>= 1) v += __shfl_down(v, off);
    if (e == 0)
        l_aux_ws[0] = v * (64.0f / (8192.0f * 8192.0f));   // l_aux
}

// ---------------------------------------------------------------------------
// Kernel 4: scatter surviving tokens + l_aux into the zeroed output
// ---------------------------------------------------------------------------
__global__ __launch_bounds__(256)
void scatter_kernel(const float* __restrict__ gate_s, const int* __restrict__ expert,
                    const int* __restrict__ rank, const int* __restrict__ chunk_base,
                    const float* __restrict__ l_aux_ws, float* __restrict__ out)
{
    int s = blockIdx.x * 256 + threadIdx.x;
    if (s == 0) out[0] = l_aux_ws[0];
    if (s >= S_TOK) return;
    int e   = expert[s];
    int loc = chunk_base[(s >> 6) * NEXP + e] + rank[s];
    if (loc < CAPTY) {
        size_t idx = 1 + (size_t)s * (NEXP * CAPTY) + (size_t)e * CAPTY + loc;
        out[idx]       = gate_s[s];     // combine1_sec
        out[idx + SEC] = 1.0f;          // dispatch_mask
    }
}

extern "C" void kernel_launch(void* const* d_in, const int* in_sizes, int n_in,
                              void* d_out, int out_size, void* d_ws, size_t ws_size,
                              hipStream_t stream)
{
    const float* x  = (const float*)d_in[0];
    const float* wg = (const float*)d_in[1];
    float* out = (float*)d_out;
    char* ws = (char*)d_ws;

    float* part      = (float*)(ws + 0);                       // 16 MB
    size_t off = (size_t)SPLITK * S_TOK * NEXP * sizeof(float);
    float* gate_s    = (float*)(ws + off);          off += 32768;
    int*   expert    = (int*)  (ws + off);          off += 32768;
    int*   rank      = (int*)  (ws + off);          off += 32768;
    int*   hist      = (int*)  (ws + off);          off += 32768;
    float* partial_g = (float*)(ws + off);          off += 32768;
    int*   chunk_b   = (int*)  (ws + off);          off += 32768;
    float* l_aux_ws  = (float*)(ws + off);

    gate_gemm_kernel<<<NBLK * SPLITK, 256, 0, stream>>>(x, wg, part);
    softmax_kernel<<<NBLK, 256, 0, stream>>>(part, gate_s, expert, rank, hist, partial_g);
    scan_kernel<<<1, 64, 0, stream>>>(hist, partial_g, chunk_b, l_aux_ws);
    // 537 MB zero-fill on the rocclr fill path (measured 6.32 TB/s in round 1)
    hipMemsetAsync(d_out, 0, (size_t)out_size * sizeof(float), stream);
    scatter_kernel<<<(S_TOK + 255) / 256, 256, 0, stream>>>(gate_s, expert, rank,
                                                            chunk_b, l_aux_ws, out);
}